// Round 5
// baseline (697.762 us; speedup 1.0000x reference)
//
#include <hip/hip_runtime.h>

typedef __bf16 bf16_t;
typedef __bf16 bf16x8 __attribute__((ext_vector_type(8)));
typedef __bf16 bf16x4 __attribute__((ext_vector_type(4)));
typedef __bf16 bf16x2 __attribute__((ext_vector_type(2)));
typedef float  f32x4  __attribute__((ext_vector_type(4)));

#define HW_ 65536
#define C_  128

// XOR swizzle: spread 16B slots (byte bits [6:4]) by row index.
__device__ __forceinline__ int swz(int r) { return ((r ^ (r >> 3)) & 7) << 4; }

#define LGKM0() asm volatile("s_waitcnt lgkmcnt(0)" ::: "memory")
__device__ __forceinline__ void BAR() {
  asm volatile("" ::: "memory");
  __builtin_amdgcn_s_barrier();
  asm volatile("" ::: "memory");
}

// =====================================================================
// Phase 1 (R4 form, known-good): map = PReLU(W*x + b).
// GEMM M=128(o), K=128(c), N=128(spatial)/WG.  Direct bf16 stores.
// HBLK: mH W32-blocked [c][w>>5][h][w&31] for attn_pv direct A-reads.
// =====================================================================
template<bool HBLK>
__device__ __forceinline__ void conv_one(char* lds, const float* __restrict__ Wsrc,
                                         const float* __restrict__ bias, float alpha,
                                         bf16_t* __restrict__ dst, size_t pb,
                                         int wv, int lr, int lq, int t, int s0)
{
  __syncthreads();
  #pragma unroll
  for (int rep = 0; rep < 16; ++rep) {
    int q = rep * 256 + t;
    int o = q >> 5, c0 = (q & 31) * 4;
    f32x4 w4 = *(const f32x4*)(Wsrc + o * C_ + c0);
    bf16x4 v;
    v[0] = (bf16_t)w4[0]; v[1] = (bf16_t)w4[1]; v[2] = (bf16_t)w4[2]; v[3] = (bf16_t)w4[3];
    *(bf16x4*)(lds + 32768 + ((o * 256 + c0 * 2) ^ swz(o))) = v;
  }
  __syncthreads();

  const f32x4 fz = {0.f, 0.f, 0.f, 0.f};
  f32x4 acc[2][8];
  #pragma unroll
  for (int mf = 0; mf < 2; ++mf)
    #pragma unroll
    for (int nf = 0; nf < 8; ++nf)
      acc[mf][nf] = fz;

  #pragma unroll
  for (int ks = 0; ks < 4; ++ks) {
    int kb = ks * 32 + lq * 8;
    bf16x8 a[2], bb[8];
    #pragma unroll
    for (int mf = 0; mf < 2; ++mf) {
      int m = wv * 32 + mf * 16 + lr;
      a[mf] = *(const bf16x8*)(lds + 32768 + ((m * 256 + kb * 2) ^ swz(m)));
    }
    #pragma unroll
    for (int nf = 0; nf < 8; ++nf) {
      int n = nf * 16 + lr;
      bb[nf] = *(const bf16x8*)(lds + ((n * 256 + kb * 2) ^ swz(n)));
    }
    #pragma unroll
    for (int mf = 0; mf < 2; ++mf)
      #pragma unroll
      for (int nf = 0; nf < 8; ++nf)
        acc[mf][nf] = __builtin_amdgcn_mfma_f32_16x16x32_bf16(a[mf], bb[nf], acc[mf][nf], 0, 0, 0);
  }

  #pragma unroll
  for (int mf = 0; mf < 2; ++mf) {
    #pragma unroll
    for (int i = 0; i < 4; ++i) {
      int o = wv * 32 + mf * 16 + lq * 4 + i;
      float bo = bias[o];
      #pragma unroll
      for (int nf = 0; nf < 8; ++nf) {
        int s = s0 + nf * 16 + lr;
        float v = acc[mf][nf][i] + bo;
        v = (v >= 0.f) ? v : alpha * v;
        size_t off;
        if (HBLK) {                       // W32-blocked [c][w>>5][h][w&31]
          int h = s >> 8, w = s & 255;
          off = pb + (size_t)o * HW_ + (size_t)(w >> 5) * 8192 + h * 32 + (w & 31);
        } else {
          off = pb + (size_t)o * HW_ + s; // natural [c][h][w]
        }
        dst[off] = (bf16_t)v;
      }
    }
  }
}

__global__ __launch_bounds__(256, 2) void conv_kernel(
    const float* __restrict__ x,
    const float* __restrict__ Wf, const float* __restrict__ bfp, const float* __restrict__ afp,
    const float* __restrict__ Wg, const float* __restrict__ bgp, const float* __restrict__ agp,
    const float* __restrict__ Wh, const float* __restrict__ bhp, const float* __restrict__ ahp,
    bf16_t* __restrict__ mF, bf16_t* __restrict__ mG, bf16_t* __restrict__ mH, int b0)
{
  __shared__ __align__(16) char lds[65536];
  const int t = threadIdx.x;
  const int bloc = blockIdx.y;
  const int s0 = blockIdx.x * 128;
  const size_t xbase = ((size_t)(b0 + bloc) * C_) * HW_ + s0;

  #pragma unroll
  for (int rep = 0; rep < 4; ++rep) {
    int q = rep * 256 + t;
    int c0 = (q >> 5) * 4, sl0 = (q & 31) * 4;
    f32x4 r[4];
    #pragma unroll
    for (int i = 0; i < 4; ++i)
      r[i] = *(const f32x4*)(x + xbase + (size_t)(c0 + i) * HW_ + sl0);
    #pragma unroll
    for (int js = 0; js < 4; ++js) {
      int s = sl0 + js;
      bf16x4 v;
      v[0] = (bf16_t)r[0][js]; v[1] = (bf16_t)r[1][js];
      v[2] = (bf16_t)r[2][js]; v[3] = (bf16_t)r[3][js];
      *(bf16x4*)(lds + ((s * 256 + c0 * 2) ^ swz(s))) = v;
    }
  }

  const int wv = t >> 6, lane = t & 63, lr = lane & 15, lq = lane >> 4;
  const size_t pb = (size_t)bloc * C_ * HW_;
  conv_one<false>(lds, Wf, bfp, afp[0], mF, pb, wv, lr, lq, t, s0);
  conv_one<false>(lds, Wg, bgp, agp[0], mG, pb, wv, lr, lq, t, s0);
  conv_one<true >(lds, Wh, bhp, ahp[0], mH, pb, wv, lr, lq, t, s0);
}

// =====================================================================
// attn_s: per (b,c,half): S = F^T[w-half] G (128x256, K=h=256), softmax
// over v, P -> bf16 -> mP as P^T layout [v=256][w=256].
// 512 thr = 8 waves (wr2 x wc4); acc 64 f32/lane; 2 WGs/CU (52 KB LDS).
// LDS: Ft [w128][h64] @0 (16K), Gt [v256][h64] @16K (32K),
//      smax[4][128] @48K, ssum[4][128] @50K.
// =====================================================================
#define AS_GT   16384
#define AS_SMAX 49152
#define AS_SSUM 51200

__global__ __launch_bounds__(512, 4) void attn_s_kernel(
    const bf16_t* __restrict__ mF, const bf16_t* __restrict__ mG,
    bf16_t* __restrict__ mP)
{
  __shared__ __align__(16) char smem[53248];
  // bijective XCD swizzle (gridDim.x % 8 == 0): plane-sharing WGs -> same XCD
  const int cpx = gridDim.x >> 3;
  const int id = (blockIdx.x & 7) * cpx + (blockIdx.x >> 3);
  const int bloc = id >> 8;            // id / (2*C_)
  const int rr = id & 255;
  const int c = rr >> 1, half = rr & 1;
  const size_t plane = ((size_t)bloc * C_ + c) * HW_;

  const int t = threadIdx.x;
  const int lane = t & 63, lr = lane & 15, lq = lane >> 4;
  const int wv = t >> 6, wr2 = wv >> 2, wc4 = wv & 3;

  const f32x4 fz = {0.f, 0.f, 0.f, 0.f};
  f32x4 acc[4][4];
  #pragma unroll
  for (int mf = 0; mf < 4; ++mf)
    #pragma unroll
    for (int nf = 0; nf < 4; ++nf)
      acc[mf][nf] = fz;

  // staging decompositions
  const int gv0 = (t & 31) * 8, gh0 = (t >> 5) * 4;   // Gt: 256v x 64h
  const int fw0 = (t & 15) * 8, fh0 = (t >> 4) * 2;   // Ft: 128w x 64h
  const bf16_t* gsrc = mG + plane;
  const bf16_t* fsrc = mF + plane + half * 128;

  bf16x8 gpf[4];
  #pragma unroll
  for (int i = 0; i < 4; ++i)
    gpf[i] = *(const bf16x8*)(gsrc + (size_t)(gh0 + i) * 256 + gv0);

  for (int hb = 0; hb < 256; hb += 64) {
    // F chunk load (L3-resident maps; no cross-chunk prefetch to save regs)
    bf16x8 f0 = *(const bf16x8*)(fsrc + (size_t)(hb + fh0) * 256 + fw0);
    bf16x8 f1 = *(const bf16x8*)(fsrc + (size_t)(hb + fh0 + 1) * 256 + fw0);
    // G transpose-write from prefetch regs
    #pragma unroll
    for (int j = 0; j < 8; ++j) {
      int v = gv0 + j;
      bf16x4 q; q[0] = gpf[0][j]; q[1] = gpf[1][j]; q[2] = gpf[2][j]; q[3] = gpf[3][j];
      *(bf16x4*)(smem + AS_GT + ((v * 128 + gh0 * 2) ^ swz(v))) = q;
    }
    if (hb < 192) {                      // prefetch next G chunk (in flight across BAR)
      #pragma unroll
      for (int i = 0; i < 4; ++i)
        gpf[i] = *(const bf16x8*)(gsrc + (size_t)(hb + 64 + gh0 + i) * 256 + gv0);
    }
    // F transpose-write
    #pragma unroll
    for (int j = 0; j < 8; ++j) {
      int w = fw0 + j;
      bf16x2 q2; q2[0] = f0[j]; q2[1] = f1[j];
      *(bf16x2*)(smem + ((w * 128 + fh0 * 2) ^ swz(w))) = q2;
    }
    LGKM0(); BAR();
    #pragma unroll
    for (int k0 = 0; k0 < 64; k0 += 32) {
      const int kb = k0 + lq * 8;
      bf16x8 af[4], bq[4];
      #pragma unroll
      for (int mf = 0; mf < 4; ++mf) {
        int m = wr2 * 64 + mf * 16 + lr;
        af[mf] = *(const bf16x8*)(smem + ((m * 128 + kb * 2) ^ swz(m)));
      }
      #pragma unroll
      for (int nf = 0; nf < 4; ++nf) {
        int n = wc4 * 64 + nf * 16 + lr;
        bq[nf] = *(const bf16x8*)(smem + AS_GT + ((n * 128 + kb * 2) ^ swz(n)));
      }
      #pragma unroll
      for (int mf = 0; mf < 4; ++mf)
        #pragma unroll
        for (int nf = 0; nf < 4; ++nf)
          acc[mf][nf] = __builtin_amdgcn_mfma_f32_16x16x32_bf16(af[mf], bq[nf], acc[mf][nf], 0, 0, 0);
    }
    BAR();
  }

  // ---- softmax over v (128 w-rows of this half) ----
  float* smax = (float*)(smem + AS_SMAX);
  float* ssum = (float*)(smem + AS_SSUM);
  float rinv[4][4];
  {
    float rowm[4][4];
    #pragma unroll
    for (int mf = 0; mf < 4; ++mf)
      #pragma unroll
      for (int i = 0; i < 4; ++i) {
        float m = fmaxf(fmaxf(acc[mf][0][i], acc[mf][1][i]),
                        fmaxf(acc[mf][2][i], acc[mf][3][i]));
        #pragma unroll
        for (int d = 1; d < 16; d <<= 1) m = fmaxf(m, __shfl_xor(m, d));
        rowm[mf][i] = m;
      }
    if (lr == 0) {
      #pragma unroll
      for (int mf = 0; mf < 4; ++mf)
        #pragma unroll
        for (int i = 0; i < 4; ++i)
          smax[wc4 * 128 + wr2 * 64 + mf * 16 + lq * 4 + i] = rowm[mf][i];
    }
    LGKM0(); BAR();
    #pragma unroll
    for (int mf = 0; mf < 4; ++mf)
      #pragma unroll
      for (int i = 0; i < 4; ++i) {
        int w = wr2 * 64 + mf * 16 + lq * 4 + i;
        rowm[mf][i] = fmaxf(fmaxf(smax[w], smax[128 + w]),
                            fmaxf(smax[256 + w], smax[384 + w]));
      }
    #pragma unroll
    for (int mf = 0; mf < 4; ++mf)
      #pragma unroll
      for (int i = 0; i < 4; ++i) {
        float rs = 0.f;
        #pragma unroll
        for (int nf = 0; nf < 4; ++nf) {
          float e = __expf(acc[mf][nf][i] - rowm[mf][i]);
          acc[mf][nf][i] = e;
          rs += e;
        }
        #pragma unroll
        for (int d = 1; d < 16; d <<= 1) rs += __shfl_xor(rs, d);
        if (lr == 0) ssum[wc4 * 128 + wr2 * 64 + mf * 16 + lq * 4 + i] = rs;
      }
    LGKM0(); BAR();
    #pragma unroll
    for (int mf = 0; mf < 4; ++mf)
      #pragma unroll
      for (int i = 0; i < 4; ++i) {
        int w = wr2 * 64 + mf * 16 + lq * 4 + i;
        rinv[mf][i] = 1.f / (ssum[w] + ssum[128 + w] + ssum[256 + w] + ssum[384 + w]);
      }
  }

  // ---- P -> bf16 -> mP (P^T layout [v][w]); i packs to 8B stores ----
  bf16_t* pp = mP + plane;
  #pragma unroll
  for (int mf = 0; mf < 4; ++mf) {
    int wb = half * 128 + wr2 * 64 + mf * 16 + lq * 4;
    #pragma unroll
    for (int nf = 0; nf < 4; ++nf) {
      int v = wc4 * 64 + nf * 16 + lr;
      bf16x4 q;
      #pragma unroll
      for (int i = 0; i < 4; ++i) q[i] = (bf16_t)(acc[mf][nf][i] * rinv[mf][i]);
      *(bf16x4*)(pp + (size_t)v * 256 + wb) = q;
    }
  }
}

// =====================================================================
// attn_pv: per (b,c,hh): out[h-half] = H[h-half]*P + x.  512 thr = 8 waves,
// wave owns 16 h-rows x 256 v; oac 64 f32/lane; 2 WGs/CU (32 KB LDS).
// B: P^T[v][w] global -> straight-copied LDS chunks [v256][w64] (32 KB,
//    row-XOR swizzled), reg-staged with cross-barrier prefetch.
// A: H direct from global (W32-blocked, 1KB contiguous per wave read,
//    read exactly once), 1-chunk-ahead prefetch.
// =====================================================================
__global__ __launch_bounds__(512, 4) void attn_pv_kernel(
    const bf16_t* __restrict__ mH, const bf16_t* __restrict__ mP,
    const float* __restrict__ x, float* __restrict__ out, int b0)
{
  __shared__ __align__(16) char smem[32768];
  const int cpx = gridDim.x >> 3;
  const int id = (blockIdx.x & 7) * cpx + (blockIdx.x >> 3);
  const int bloc = id >> 8;
  const int rr = id & 255;
  const int c = rr >> 1, hh = rr & 1;
  const size_t plane  = ((size_t)bloc * C_ + c) * HW_;
  const size_t gplane = ((size_t)(b0 + bloc) * C_ + c) * HW_;

  const int t = threadIdx.x;
  const int lane = t & 63, lr = lane & 15, lq = lane >> 4;
  const int wv = t >> 6;

  const bf16_t* pp = mP + plane;
  const bf16_t* hp = mH + plane;
  const int ha = (hh * 128 + wv * 16 + lr) * 32 + lq * 8;

  // stage regs for chunk 0: [v256][w64] = 2048 16B slots / 512 thr
  bf16x8 sreg[4];
  #pragma unroll
  for (int r = 0; r < 4; ++r) {
    int q = r * 512 + t; int v = q >> 3, s = q & 7;
    sreg[r] = *(const bf16x8*)(pp + (size_t)v * 256 + s * 8);
  }
  bf16x8 aCur[2], aNxt[2];
  #pragma unroll
  for (int b2 = 0; b2 < 2; ++b2)
    aCur[b2] = *(const bf16x8*)(hp + (size_t)b2 * 8192 + ha);

  const f32x4 fz = {0.f, 0.f, 0.f, 0.f};
  f32x4 oac[16];
  #pragma unroll
  for (int nf = 0; nf < 16; ++nf) oac[nf] = fz;

  #pragma unroll
  for (int ch = 0; ch < 4; ++ch) {
    // write staged P chunk to LDS (vmcnt auto-waited on sreg)
    #pragma unroll
    for (int r = 0; r < 4; ++r) {
      int q = r * 512 + t; int v = q >> 3, s = q & 7;
      *(bf16x8*)(smem + ((v * 128 + s * 16) ^ ((v & 7) << 4))) = sreg[r];
    }
    LGKM0(); BAR();
    if (ch < 3) {            // prefetch next P chunk + next H blocks (fly across BAR)
      #pragma unroll
      for (int r = 0; r < 4; ++r) {
        int q = r * 512 + t; int v = q >> 3, s = q & 7;
        sreg[r] = *(const bf16x8*)(pp + (size_t)v * 256 + (ch + 1) * 64 + s * 8);
      }
      #pragma unroll
      for (int b2 = 0; b2 < 2; ++b2)
        aNxt[b2] = *(const bf16x8*)(hp + (size_t)((ch + 1) * 2 + b2) * 8192 + ha);
    }
    __builtin_amdgcn_s_setprio(1);
    #pragma unroll
    for (int k2 = 0; k2 < 2; ++k2) {
      const int kb = k2 * 32 + lq * 8;
      #pragma unroll
      for (int nf = 0; nf < 16; ++nf) {
        int v = nf * 16 + lr;
        bf16x8 bq = *(const bf16x8*)(smem + ((v * 128 + kb * 2) ^ ((v & 7) << 4)));
        oac[nf] = __builtin_amdgcn_mfma_f32_16x16x32_bf16(aCur[k2], bq, oac[nf], 0, 0, 0);
      }
    }
    __builtin_amdgcn_s_setprio(0);
    aCur[0] = aNxt[0]; aCur[1] = aNxt[1];
    BAR();
  }

  // ---- residual + store f32 (wave writes its 16 rows fully) ----
  #pragma unroll
  for (int i = 0; i < 4; ++i) {
    int h = hh * 128 + wv * 16 + lq * 4 + i;
    #pragma unroll
    for (int nf = 0; nf < 16; ++nf) {
      int v = nf * 16 + lr;
      size_t off = gplane + (size_t)h * 256 + v;
      out[off] = oac[nf][i] + x[off];
    }
  }
}

// =====================================================================
extern "C" void kernel_launch(void* const* d_in, const int* in_sizes, int n_in,
                              void* d_out, int out_size, void* d_ws, size_t ws_size,
                              hipStream_t stream)
{
  (void)in_sizes; (void)n_in; (void)out_size;
  const float* x   = (const float*)d_in[0];
  const float* Wf  = (const float*)d_in[1];
  const float* bfp = (const float*)d_in[2];
  const float* afp = (const float*)d_in[3];
  const float* Wg  = (const float*)d_in[4];
  const float* bgp = (const float*)d_in[5];
  const float* agp = (const float*)d_in[6];
  const float* Wh  = (const float*)d_in[7];
  const float* bhp = (const float*)d_in[8];
  const float* ahp = (const float*)d_in[9];
  float* out = (float*)d_out;

  const size_t per_plane_b = (size_t)C_ * HW_ * sizeof(bf16_t);  // 16 MiB per (buffer, batch)
  // nb=2: maps+P working set = 4 x 2 x 16 MB = 128 MB <= L3 (256 MB) with
  // headroom for the x/out streams -> map & P traffic stays in Infinity Cache.
  int nb = (ws_size >= 4 * 2 * per_plane_b) ? 2 : 1;

  bf16_t* mF = (bf16_t*)d_ws;
  bf16_t* mG = mF + (size_t)nb * C_ * HW_;
  bf16_t* mH = mG + (size_t)nb * C_ * HW_;
  bf16_t* mP = mH + (size_t)nb * C_ * HW_;

  for (int b0 = 0; b0 < 8; b0 += nb) {
    conv_kernel<<<dim3(512, nb), 256, 0, stream>>>(x, Wf, bfp, afp, Wg, bgp, agp,
                                                   Wh, bhp, ahp, mF, mG, mH, b0);
    attn_s_kernel<<<dim3(2 * C_ * nb), 512, 0, stream>>>(mF, mG, mP);
    attn_pv_kernel<<<dim3(2 * C_ * nb), 512, 0, stream>>>(mH, mP, x, out, b0);
  }
}

// Round 7
// 434.459 us; speedup vs baseline: 1.6060x; 1.6060x over previous
//
#include <hip/hip_runtime.h>

typedef __bf16 bf16_t;
typedef __bf16 bf16x8 __attribute__((ext_vector_type(8)));
typedef __bf16 bf16x4 __attribute__((ext_vector_type(4)));
typedef float  f32x4  __attribute__((ext_vector_type(4)));

#define HW_ 65536
#define C_  128

// XOR swizzle: spread 16B slots (byte bits [6:4]) by row index.
__device__ __forceinline__ int swz(int r) { return ((r ^ (r >> 3)) & 7) << 4; }

#define LGKM0() asm volatile("s_waitcnt lgkmcnt(0)" ::: "memory")
__device__ __forceinline__ void BAR() {
  asm volatile("" ::: "memory");
  __builtin_amdgcn_s_barrier();
  asm volatile("" ::: "memory");
}

// =====================================================================
// Phase 1 (R1 form, measured 154us): map = PReLU(W*x + b).
// GEMM M=128(o), K=128(c), N=128(spatial)/WG.  Direct bf16 stores.
// HBLK: mH W32-blocked [c][w>>5][h][w&31] for attn PV direct A-reads.
// =====================================================================
template<bool HBLK>
__device__ __forceinline__ void conv_one(char* lds, const float* __restrict__ Wsrc,
                                         const float* __restrict__ bias, float alpha,
                                         bf16_t* __restrict__ dst, size_t pb,
                                         int wv, int lr, int lq, int t, int s0)
{
  __syncthreads();
  #pragma unroll
  for (int rep = 0; rep < 16; ++rep) {
    int q = rep * 256 + t;
    int o = q >> 5, c0 = (q & 31) * 4;
    f32x4 w4 = *(const f32x4*)(Wsrc + o * C_ + c0);
    bf16x4 v;
    v[0] = (bf16_t)w4[0]; v[1] = (bf16_t)w4[1]; v[2] = (bf16_t)w4[2]; v[3] = (bf16_t)w4[3];
    *(bf16x4*)(lds + 32768 + ((o * 256 + c0 * 2) ^ swz(o))) = v;
  }
  __syncthreads();

  const f32x4 fz = {0.f, 0.f, 0.f, 0.f};
  f32x4 acc[2][8];
  #pragma unroll
  for (int mf = 0; mf < 2; ++mf)
    #pragma unroll
    for (int nf = 0; nf < 8; ++nf)
      acc[mf][nf] = fz;

  #pragma unroll
  for (int ks = 0; ks < 4; ++ks) {
    int kb = ks * 32 + lq * 8;
    bf16x8 a[2], bb[8];
    #pragma unroll
    for (int mf = 0; mf < 2; ++mf) {
      int m = wv * 32 + mf * 16 + lr;
      a[mf] = *(const bf16x8*)(lds + 32768 + ((m * 256 + kb * 2) ^ swz(m)));
    }
    #pragma unroll
    for (int nf = 0; nf < 8; ++nf) {
      int n = nf * 16 + lr;
      bb[nf] = *(const bf16x8*)(lds + ((n * 256 + kb * 2) ^ swz(n)));
    }
    #pragma unroll
    for (int mf = 0; mf < 2; ++mf)
      #pragma unroll
      for (int nf = 0; nf < 8; ++nf)
        acc[mf][nf] = __builtin_amdgcn_mfma_f32_16x16x32_bf16(a[mf], bb[nf], acc[mf][nf], 0, 0, 0);
  }

  #pragma unroll
  for (int mf = 0; mf < 2; ++mf) {
    #pragma unroll
    for (int i = 0; i < 4; ++i) {
      int o = wv * 32 + mf * 16 + lq * 4 + i;
      float bo = bias[o];
      #pragma unroll
      for (int nf = 0; nf < 8; ++nf) {
        int s = s0 + nf * 16 + lr;
        float v = acc[mf][nf][i] + bo;
        v = (v >= 0.f) ? v : alpha * v;
        size_t off;
        if (HBLK) {                       // W32-blocked [c][w>>5][h][w&31]
          int h = s >> 8, w = s & 255;
          off = pb + (size_t)o * HW_ + (size_t)(w >> 5) * 8192 + h * 32 + (w & 31);
        } else {
          off = pb + (size_t)o * HW_ + s; // natural [c][h][w]
        }
        dst[off] = (bf16_t)v;
      }
    }
  }
}

__global__ __launch_bounds__(256, 2) void conv_kernel(
    const float* __restrict__ x,
    const float* __restrict__ Wf, const float* __restrict__ bfp, const float* __restrict__ afp,
    const float* __restrict__ Wg, const float* __restrict__ bgp, const float* __restrict__ agp,
    const float* __restrict__ Wh, const float* __restrict__ bhp, const float* __restrict__ ahp,
    bf16_t* __restrict__ mF, bf16_t* __restrict__ mG, bf16_t* __restrict__ mH, int b0)
{
  __shared__ __align__(16) char lds[65536];
  const int t = threadIdx.x;
  const int bloc = blockIdx.y;
  const int s0 = blockIdx.x * 128;
  const size_t xbase = ((size_t)(b0 + bloc) * C_) * HW_ + s0;

  #pragma unroll
  for (int rep = 0; rep < 4; ++rep) {
    int q = rep * 256 + t;
    int c0 = (q >> 5) * 4, sl0 = (q & 31) * 4;
    f32x4 r[4];
    #pragma unroll
    for (int i = 0; i < 4; ++i)
      r[i] = *(const f32x4*)(x + xbase + (size_t)(c0 + i) * HW_ + sl0);
    #pragma unroll
    for (int js = 0; js < 4; ++js) {
      int s = sl0 + js;
      bf16x4 v;
      v[0] = (bf16_t)r[0][js]; v[1] = (bf16_t)r[1][js];
      v[2] = (bf16_t)r[2][js]; v[3] = (bf16_t)r[3][js];
      *(bf16x4*)(lds + ((s * 256 + c0 * 2) ^ swz(s))) = v;
    }
  }

  const int wv = t >> 6, lane = t & 63, lr = lane & 15, lq = lane >> 4;
  const size_t pb = (size_t)bloc * C_ * HW_;
  conv_one<false>(lds, Wf, bfp, afp[0], mF, pb, wv, lr, lq, t, s0);
  conv_one<false>(lds, Wg, bgp, agp[0], mG, pb, wv, lr, lq, t, s0);
  conv_one<true >(lds, Wh, bhp, ahp[0], mH, pb, wv, lr, lq, t, s0);
}

// =====================================================================
// Phase 2 (R1 structure + 2 deltas): 512 thr / 8 waves, per (b,c) plane.
//  S phase : R1 wave split (wr x wc), acc[4][8]; R1 staging with next-chunk
//            global prefetch kept in flight across raw barriers.
//  softmax : R1 code; smax/ssum in dedicated region above PT.
//  PV      : wave owns 32 unique h-rows x 256 v; A = H direct from global
//            (W32-blocked, 1KB contiguous wave reads, fetched once, 3-deep
//            pipeline); B = PT LDS (one read feeds both A-frags); no barriers.
// LDS (135168 B): [0,64K) Ft|Gt -> reused as PT[v=256][w=256] [0,128K);
//                 smax f32[2][256] @128K, ssum @130K.
// =====================================================================
#define SMAX_OFF 131072
#define SSUM_OFF 133120
#define ATTN_SMEM 135168

__global__ __launch_bounds__(512, 2) void attn_kernel(
    const bf16_t* __restrict__ mF, const bf16_t* __restrict__ mG, const bf16_t* __restrict__ mH,
    const float* __restrict__ x, float* __restrict__ out, int b0)
{
  extern __shared__ __align__(16) char smem[];
  const int t = threadIdx.x;
  const int c = blockIdx.x, bloc = blockIdx.y;
  const int lane = t & 63, lr = lane & 15, lq = lane >> 4;
  const int wv = t >> 6, wr = wv >> 1, wc = wv & 1;
  const size_t plane  = ((size_t)bloc * C_ + c) * HW_;
  const size_t gplane = (((size_t)(b0 + bloc)) * C_ + c) * HW_;

  const f32x4 fz = {0.f, 0.f, 0.f, 0.f};
  f32x4 acc[4][8];
  #pragma unroll
  for (int mf = 0; mf < 4; ++mf)
    #pragma unroll
    for (int nf = 0; nf < 8; ++nf)
      acc[mf][nf] = fz;

  const int hq = t >> 5, wb8 = t & 31;   // staging decomposition (R1)

  // ---- S = F^T G, 4 h-chunks of 64, prefetch alive across barriers ----
  bf16x8 pfF[4], pfG[4];
  #pragma unroll
  for (int i = 0; i < 4; ++i) {
    pfF[i] = *(const bf16x8*)(mF + plane + (size_t)(hq * 4 + i) * 256 + wb8 * 8);
    pfG[i] = *(const bf16x8*)(mG + plane + (size_t)(hq * 4 + i) * 256 + wb8 * 8);
  }

  #pragma unroll
  for (int hb = 0; hb < 256; hb += 64) {
    #pragma unroll
    for (int j = 0; j < 8; ++j) {
      int w = wb8 * 8 + j;
      bf16x4 v; v[0] = pfF[0][j]; v[1] = pfF[1][j]; v[2] = pfF[2][j]; v[3] = pfF[3][j];
      *(bf16x4*)(smem + ((w * 128 + hq * 8) ^ swz(w))) = v;
      bf16x4 g; g[0] = pfG[0][j]; g[1] = pfG[1][j]; g[2] = pfG[2][j]; g[3] = pfG[3][j];
      *(bf16x4*)(smem + 32768 + ((w * 128 + hq * 8) ^ swz(w))) = g;
    }
    if (hb < 192) {                    // issue next chunk; flies across BAR
      #pragma unroll
      for (int i = 0; i < 4; ++i) {
        pfF[i] = *(const bf16x8*)(mF + plane + (size_t)(hb + 64 + hq * 4 + i) * 256 + wb8 * 8);
        pfG[i] = *(const bf16x8*)(mG + plane + (size_t)(hb + 64 + hq * 4 + i) * 256 + wb8 * 8);
      }
    }
    LGKM0(); BAR();
    #pragma unroll
    for (int k0 = 0; k0 < 64; k0 += 32) {
      const int kb = k0 + lq * 8;
      bf16x8 af[4], bq[8];
      #pragma unroll
      for (int mf = 0; mf < 4; ++mf) {
        int m = wr * 64 + mf * 16 + lr;
        af[mf] = *(const bf16x8*)(smem + ((m * 128 + kb * 2) ^ swz(m)));
      }
      #pragma unroll
      for (int nf = 0; nf < 8; ++nf) {
        int n = wc * 128 + nf * 16 + lr;
        bq[nf] = *(const bf16x8*)(smem + 32768 + ((n * 128 + kb * 2) ^ swz(n)));
      }
      #pragma unroll
      for (int mf = 0; mf < 4; ++mf)
        #pragma unroll
        for (int nf = 0; nf < 8; ++nf)
          acc[mf][nf] = __builtin_amdgcn_mfma_f32_16x16x32_bf16(af[mf], bq[nf], acc[mf][nf], 0, 0, 0);
    }
    BAR();
  }

  // ---- softmax over v (rows w), R1 code ----
  float* smax = (float*)(smem + SMAX_OFF);
  float* ssum = (float*)(smem + SSUM_OFF);
  float rowm[4][4];
  #pragma unroll
  for (int mf = 0; mf < 4; ++mf)
    #pragma unroll
    for (int i = 0; i < 4; ++i) {
      float m = acc[mf][0][i];
      #pragma unroll
      for (int nf = 1; nf < 8; ++nf) m = fmaxf(m, acc[mf][nf][i]);
      #pragma unroll
      for (int d = 1; d < 16; d <<= 1) m = fmaxf(m, __shfl_xor(m, d));
      rowm[mf][i] = m;
    }
  if (lr == 0) {
    #pragma unroll
    for (int mf = 0; mf < 4; ++mf)
      #pragma unroll
      for (int i = 0; i < 4; ++i)
        smax[wc * 256 + wr * 64 + mf * 16 + lq * 4 + i] = rowm[mf][i];
  }
  LGKM0(); BAR();
  float m2[4][4], rs[4][4];
  #pragma unroll
  for (int mf = 0; mf < 4; ++mf)
    #pragma unroll
    for (int i = 0; i < 4; ++i) {
      int w = wr * 64 + mf * 16 + lq * 4 + i;
      m2[mf][i] = fmaxf(smax[w], smax[256 + w]);
      rs[mf][i] = 0.f;
    }
  #pragma unroll
  for (int mf = 0; mf < 4; ++mf)
    #pragma unroll
    for (int nf = 0; nf < 8; ++nf)
      #pragma unroll
      for (int i = 0; i < 4; ++i) {
        float e = __expf(acc[mf][nf][i] - m2[mf][i]);
        acc[mf][nf][i] = e;
        rs[mf][i] += e;
      }
  #pragma unroll
  for (int mf = 0; mf < 4; ++mf)
    #pragma unroll
    for (int i = 0; i < 4; ++i) {
      float s = rs[mf][i];
      #pragma unroll
      for (int d = 1; d < 16; d <<= 1) s += __shfl_xor(s, d);
      rs[mf][i] = s;
    }
  if (lr == 0) {
    #pragma unroll
    for (int mf = 0; mf < 4; ++mf)
      #pragma unroll
      for (int i = 0; i < 4; ++i)
        ssum[wc * 256 + wr * 64 + mf * 16 + lq * 4 + i] = rs[mf][i];
  }
  LGKM0(); BAR();

  // ---- P = e/sum -> bf16 -> PT[v][w] (i-packed 8B writes) ----
  #pragma unroll
  for (int mf = 0; mf < 4; ++mf) {
    float rinv[4];
    #pragma unroll
    for (int i = 0; i < 4; ++i) {
      int w = wr * 64 + mf * 16 + lq * 4 + i;
      rinv[i] = 1.f / (ssum[w] + ssum[256 + w]);
    }
    int wpb = (wr * 64 + mf * 16 + lq * 4) * 2;
    #pragma unroll
    for (int nf = 0; nf < 8; ++nf) {
      int v_ = wc * 128 + nf * 16 + lr;
      bf16x4 v;
      #pragma unroll
      for (int i = 0; i < 4; ++i) v[i] = (bf16_t)(acc[mf][nf][i] * rinv[i]);
      *(bf16x4*)(smem + ((v_ * 512 + wpb) ^ swz(v_))) = v;
    }
  }

  // ---- prefetch H chunks 0..2 (wave owns h rows [wv*32, wv*32+32)) ----
  const bf16_t* hp = mH + plane;
  bf16x8 aP[3][2];
  #pragma unroll
  for (int p = 0; p < 3; ++p)
    #pragma unroll
    for (int mf = 0; mf < 2; ++mf) {
      int h = wv * 32 + mf * 16 + lr;
      aP[p][mf] = *(const bf16x8*)(hp + (size_t)p * 8192 + h * 32 + lq * 8);
    }

  LGKM0(); BAR();   // PT visible; H prefetch stays in flight (vmcnt alive)

  // ---- out = H*P: 8 w-chunks x 16 v-frags, H read once, ZERO barriers ----
  f32x4 oac[2][16];
  #pragma unroll
  for (int mf = 0; mf < 2; ++mf)
    #pragma unroll
    for (int nf = 0; nf < 16; ++nf)
      oac[mf][nf] = fz;

  __builtin_amdgcn_s_setprio(1);
  #pragma unroll
  for (int kc = 0; kc < 8; ++kc) {
    bf16x8 a0 = aP[kc % 3][0], a1 = aP[kc % 3][1];
    if (kc < 5) {
      #pragma unroll
      for (int mf = 0; mf < 2; ++mf) {
        int h = wv * 32 + mf * 16 + lr;
        aP[kc % 3][mf] = *(const bf16x8*)(hp + (size_t)(kc + 3) * 8192 + h * 32 + lq * 8);
      }
    }
    #pragma unroll
    for (int nf = 0; nf < 16; ++nf) {
      int v_ = nf * 16 + lr;
      bf16x8 bq = *(const bf16x8*)(smem + ((v_ * 512 + kc * 64 + lq * 16) ^ swz(v_)));
      oac[0][nf] = __builtin_amdgcn_mfma_f32_16x16x32_bf16(a0, bq, oac[0][nf], 0, 0, 0);
      oac[1][nf] = __builtin_amdgcn_mfma_f32_16x16x32_bf16(a1, bq, oac[1][nf], 0, 0, 0);
    }
  }
  __builtin_amdgcn_s_setprio(0);

  // ---- residual + store f32 (wave writes its 32 rows fully) ----
  #pragma unroll
  for (int mf = 0; mf < 2; ++mf)
    #pragma unroll
    for (int i = 0; i < 4; ++i) {
      int h = wv * 32 + mf * 16 + lq * 4 + i;
      #pragma unroll
      for (int nf = 0; nf < 16; ++nf) {
        int v_ = nf * 16 + lr;
        size_t off = gplane + (size_t)h * 256 + v_;
        out[off] = oac[mf][nf][i] + x[off];
      }
    }
}

// =====================================================================
extern "C" void kernel_launch(void* const* d_in, const int* in_sizes, int n_in,
                              void* d_out, int out_size, void* d_ws, size_t ws_size,
                              hipStream_t stream)
{
  (void)in_sizes; (void)n_in; (void)out_size;
  const float* x   = (const float*)d_in[0];
  const float* Wf  = (const float*)d_in[1];
  const float* bfp = (const float*)d_in[2];
  const float* afp = (const float*)d_in[3];
  const float* Wg  = (const float*)d_in[4];
  const float* bgp = (const float*)d_in[5];
  const float* agp = (const float*)d_in[6];
  const float* Wh  = (const float*)d_in[7];
  const float* bhp = (const float*)d_in[8];
  const float* ahp = (const float*)d_in[9];
  float* out = (float*)d_out;

  const size_t per_map_b = (size_t)C_ * HW_ * sizeof(bf16_t);  // 16 MiB per map per batch
  int nb = 1;
  if      (ws_size >= 3 * 8 * per_map_b) nb = 8;
  else if (ws_size >= 3 * 4 * per_map_b) nb = 4;
  else if (ws_size >= 3 * 2 * per_map_b) nb = 2;

  hipFuncSetAttribute(reinterpret_cast<const void*>(attn_kernel),
                      hipFuncAttributeMaxDynamicSharedMemorySize, ATTN_SMEM);

  bf16_t* mF = (bf16_t*)d_ws;
  bf16_t* mG = mF + (size_t)nb * C_ * HW_;
  bf16_t* mH = mG + (size_t)nb * C_ * HW_;

  for (int b0 = 0; b0 < 8; b0 += nb) {
    conv_kernel<<<dim3(512, nb), 256, 0, stream>>>(x, Wf, bfp, afp, Wg, bgp, agp,
                                                   Wh, bhp, ahp, mF, mG, mH, b0);
    attn_kernel<<<dim3(C_, nb), 512, ATTN_SMEM, stream>>>(mF, mG, mH, x, out, b0);
  }
}